// Round 6
// baseline (282.199 us; speedup 1.0000x reference)
//
#include <hip/hip_runtime.h>

typedef unsigned short u16;
typedef unsigned int u32;
typedef __bf16 bfx8 __attribute__((ext_vector_type(8)));
typedef float f32x4 __attribute__((ext_vector_type(4)));

#define Tn 8192
#define Bn 4
#define MTOT 32768
#define CH 128
#define TC 64

// ---- ws layout (bytes) ----
#define OFF_W     0ul
#define OFF_AL2   917504ul
#define OFF_XN    (1ul<<20)    // 16 MiB
#define OFF_XIN   (17ul<<20)   // 32 MiB (reused as ygated)
#define OFF_Z     (49ul<<20)   // 32 MiB
#define OFF_U     (81ul<<20)   // 32 MiB
#define OFF_DBLDT (113ul<<20)  // 2 MiB  (dt bf16 padded, 32 u16/row)
#define OFF_BCF   (115ul<<20)  // 4 MiB  (B|C f32, 32 f32/row)
#define OFF_DELTA (119ul<<20)  // 32 MiB (delta bf16)
#define OFF_P     (151ul<<20)  // 16 MiB (becomes h0 after pass B)
#define OFF_CC    (167ul<<20)  // 16 MiB ; total 183 MiB

__device__ __forceinline__ float b2f(u16 h){ return __uint_as_float(((u32)h)<<16); }
__device__ __forceinline__ u16 f2b(float f){
  u32 u = __float_as_uint(f);
  return (u16)((u + 0x7FFFu + ((u>>16)&1u)) >> 16);
}
__device__ __forceinline__ float aexp2(float x){ float r; asm("v_exp_f32 %0, %1" : "=v"(r) : "v"(x)); return r; }
__device__ __forceinline__ float arcp (float x){ float r; asm("v_rcp_f32 %0, %1" : "=v"(r) : "v"(x)); return r; }
__device__ __forceinline__ float alog2(float x){ float r; asm("v_log_f32 %0, %1" : "=v"(r) : "v"(x)); return r; }
__device__ __forceinline__ float fsilu(float a){ return a*arcp(1.f + aexp2(-a*1.44269504f)); }
__device__ __forceinline__ float fsoftplus(float v){
  float r = 0.69314718f*alog2(1.f + aexp2(v*1.44269504f));
  return (v > 20.f) ? v : r;
}
typedef const __attribute__((address_space(1))) void* gp1_t;
typedef __attribute__((address_space(3))) void* lp3_t;
__device__ __forceinline__ void gload_lds16(const void* g, void* l){
  __builtin_amdgcn_global_load_lds((gp1_t)g, (lp3_t)l, 16, 0, 0);
}

// ---------------- weight convert / pad / A-table ----------------
__global__ void wconv_k(const float* __restrict__ inw, const float* __restrict__ xpw,
                        const float* __restrict__ dtw, const float* __restrict__ opw,
                        const float* __restrict__ alog, u16* __restrict__ W, float* __restrict__ aL2)
{
  int i = blockIdx.x*256 + threadIdx.x;
  if (i < 262144) { W[i] = f2b(inw[i]); return; }                       // in_proj (1024x256)
  if (i < 294912) { int j = i - 262144; int r = j >> 9, k = j & 511;    // x_proj padded (64x512)
    float v = (r < 16) ? xpw[r*512 + k] : ((r < 32) ? 0.f : xpw[(r-16)*512 + k]);
    W[i] = f2b(v); return; }
  if (i < 311296) { int j = i - 294912; int d = j >> 5, k = j & 31;     // dt_proj padded (512x32)
    W[i] = f2b((k < 16) ? dtw[d*16 + k] : 0.f); return; }
  if (i < 442368) { W[i] = f2b(opw[i - 311296]); return; }              // out_proj (256x512)
  if (i < 450560) { int j = i - 442368; aL2[j] = -__expf(alog[j]) * 1.44269504088896f; return; }
}

// ---------------- LayerNorm over C, write xn (B,T,C) bf16 ----------------
__global__ __launch_bounds__(256)
void ln_k(const float* __restrict__ x, const float* __restrict__ lnw,
          const float* __restrict__ lnb, u16* __restrict__ xn)
{
  const int t0 = blockIdx.x*64, b = blockIdx.y;
  const int tid = threadIdx.x, cg = tid>>6, tl = tid&63;
  __shared__ float ps[4][64], pq[4][64], mu[64], rs[64];
  float s = 0.f, q = 0.f;
  for (int ci = 0; ci < 64; ci++){
    int c = ci*4 + cg;
    float v = x[((size_t)(b*256 + c))*Tn + t0 + tl];
    s += v; q += v*v;
  }
  ps[cg][tl] = s; pq[cg][tl] = q;
  __syncthreads();
  if (tid < 64){
    float S = ps[0][tid]+ps[1][tid]+ps[2][tid]+ps[3][tid];
    float Q = pq[0][tid]+pq[1][tid]+pq[2][tid]+pq[3][tid];
    float m = S*(1.f/256.f);
    float var = Q*(1.f/256.f) - m*m;
    mu[tid] = m; rs[tid] = rsqrtf(var + 1e-5f);
  }
  __syncthreads();
  const float w = lnw[tid&255], bb = lnb[tid&255];
  for (int t = 0; t < 64; t++){
    float v = x[((size_t)(b*256 + tid))*Tn + t0 + t];
    xn[((size_t)(b*Tn) + t0 + t)*256 + tid] = f2b((v - mu[t])*rs[t]*w + bb);
  }
}

// ---------------- generic bf16 MFMA GEMM: out[m][n] = sum_k A[m][k]*Bw[n][k] ----------------
// EPI 1: softplus(v+bias[n]) bf16 ; 2: split col<512->O else O2 ; 3: col<32->O bf16 (32/row) else Of f32 (32/row)
template<int BN, int EPI>
__global__ __launch_bounds__(256)
void gemm_k(const u16* __restrict__ A, int lda,
            const u16* __restrict__ Bw, int ldb,
            u16* __restrict__ O, u16* __restrict__ O2, float* __restrict__ Of, int ldo,
            const float* __restrict__ bias, int K)
{
  constexpr int NFR = BN/32;
  __shared__ __align__(16) u16 sA[128*32];
  __shared__ __align__(16) u16 sB[BN*32];
  const int tid = threadIdx.x;
  const int m0 = blockIdx.x*128, n0 = blockIdx.y*BN;
  const int lane = tid & 63, wid = tid >> 6;
  const int wr = wid >> 1, wc = wid & 1;
  const int lr = lane & 15, g = lane >> 4;
  const f32x4 fz = {0.f,0.f,0.f,0.f};
  f32x4 acc[4][NFR];
  #pragma unroll
  for (int m=0;m<4;m++)
    #pragma unroll
    for (int n=0;n<NFR;n++) acc[m][n] = fz;
  const int nk = K >> 5;
  for (int kt = 0; kt < nk; ++kt){
    __syncthreads();
    #pragma unroll
    for (int i=0;i<2;i++){ int ci = i*256 + tid;
      gload_lds16(A + (size_t)(m0+(ci>>2))*lda + kt*32 + (ci&3)*8, sA + ci*8); }
    #pragma unroll
    for (int i=0;i<BN/64;i++){ int ci = i*256 + tid;
      gload_lds16(Bw + (size_t)(n0+(ci>>2))*ldb + kt*32 + (ci&3)*8, sB + ci*8); }
    __syncthreads();
    bfx8 af[4], bf[NFR];
    #pragma unroll
    for (int m=0;m<4;m++) af[m] = *(const bfx8*)(sA + (wr*64 + m*16 + lr)*32 + g*8);
    #pragma unroll
    for (int n=0;n<NFR;n++) bf[n] = *(const bfx8*)(sB + (wc*(BN/2) + n*16 + lr)*32 + g*8);
    #pragma unroll
    for (int m=0;m<4;m++)
      #pragma unroll
      for (int n=0;n<NFR;n++)
        acc[m][n] = __builtin_amdgcn_mfma_f32_16x16x32_bf16(af[m], bf[n], acc[m][n], 0, 0, 0);
  }
  #pragma unroll
  for (int m=0;m<4;m++)
    #pragma unroll
    for (int n=0;n<NFR;n++)
      #pragma unroll
      for (int r=0;r<4;r++){
        int row = m0 + wr*64 + m*16 + g*4 + r;
        int col = n0 + wc*(BN/2) + n*16 + lr;
        float v = acc[m][n][r];
        if (EPI == 1){
          O[(size_t)row*ldo + col] = f2b(fsoftplus(v + bias[col]));
        } else if (EPI == 2){
          if (col < 512) O[(size_t)row*512 + col] = f2b(v);
          else           O2[(size_t)row*512 + (col-512)] = f2b(v);
        } else {
          if (col < 32) O[(size_t)row*32 + col] = f2b(v);
          else          Of[(size_t)row*32 + (col-32)] = v;
        }
      }
}

// ---------------- out_proj GEMM fused with transpose + residual: out (B,C,T) f32 ----------------
__global__ __launch_bounds__(256)
void gemmot_k(const u16* __restrict__ A, const u16* __restrict__ Bw,
              const float* __restrict__ x, float* __restrict__ out)
{
  __shared__ __align__(16) u16 sA[128*32];
  __shared__ __align__(16) u16 sB[128*32];
  __shared__ float st[64][129];
  const int tid = threadIdx.x;
  const int m0 = blockIdx.x*128, n0 = blockIdx.y*128;
  const int lane = tid & 63, wid = tid >> 6;
  const int wr = wid >> 1, wc = wid & 1;
  const int lr = lane & 15, g = lane >> 4;
  const f32x4 fz = {0.f,0.f,0.f,0.f};
  f32x4 acc[4][4];
  #pragma unroll
  for (int m=0;m<4;m++)
    #pragma unroll
    for (int n=0;n<4;n++) acc[m][n] = fz;
  for (int kt = 0; kt < 16; ++kt){
    __syncthreads();
    #pragma unroll
    for (int i=0;i<2;i++){ int ci = i*256 + tid;
      gload_lds16(A + (size_t)(m0+(ci>>2))*512 + kt*32 + (ci&3)*8, sA + ci*8); }
    #pragma unroll
    for (int i=0;i<2;i++){ int ci = i*256 + tid;
      gload_lds16(Bw + (size_t)(n0+(ci>>2))*512 + kt*32 + (ci&3)*8, sB + ci*8); }
    __syncthreads();
    bfx8 af[4], bf[4];
    #pragma unroll
    for (int m=0;m<4;m++) af[m] = *(const bfx8*)(sA + (wr*64 + m*16 + lr)*32 + g*8);
    #pragma unroll
    for (int n=0;n<4;n++) bf[n] = *(const bfx8*)(sB + (wc*64 + n*16 + lr)*32 + g*8);
    #pragma unroll
    for (int m=0;m<4;m++)
      #pragma unroll
      for (int n=0;n<4;n++)
        acc[m][n] = __builtin_amdgcn_mfma_f32_16x16x32_bf16(af[m], bf[n], acc[m][n], 0, 0, 0);
  }
  const int b = m0 >> 13, t0 = m0 & 8191;
  const int tl = tid & 63, cgrp = tid >> 6;
  for (int hf=0; hf<2; hf++){
    __syncthreads();
    if (wr == hf){
      #pragma unroll
      for (int m=0;m<4;m++)
        #pragma unroll
        for (int n=0;n<4;n++)
          #pragma unroll
          for (int r=0;r<4;r++)
            st[m*16 + g*4 + r][wc*64 + n*16 + lr] = acc[m][n][r];
    }
    __syncthreads();
    const int tg = t0 + hf*64 + tl;
    #pragma unroll
    for (int ci=0; ci<32; ci++){
      int c = cgrp*32 + ci;
      size_t oa = ((size_t)(b*256) + n0 + c)*Tn + tg;
      out[oa] = st[tl][c] + x[oa];
    }
  }
}

// ---------------- causal depthwise conv (k=4) + bias + silu -> u bf16 ----------------
__global__ __launch_bounds__(256)
void conv_k(const u16* __restrict__ xin, const float* __restrict__ cw,
            const float* __restrict__ cb, u16* __restrict__ u)
{
  const int t0 = blockIdx.x*32, d0 = blockIdx.y*64, b = blockIdx.z;
  const int tid = threadIdx.x;
  __shared__ float sx[35][64];
  __shared__ float sw[4][64];
  { int d = tid>>2, j = tid&3; sw[j][d] = cw[(d0+d)*4 + j]; }
  for (int i=0;i<9;i++){ int f = i*256 + tid; if (f < 35*64){
      int r = f>>6, dd = f&63; int t = t0 - 3 + r;
      sx[r][dd] = (t >= 0) ? b2f(xin[((size_t)(b*Tn)+t)*512 + d0+dd]) : 0.f; } }
  __syncthreads();
  const float cbv = cb[d0 + (tid&63)];
  for (int oi=0; oi<8; oi++){
    int f = oi*256 + tid; int tr = f>>6, dd = f&63;
    float a = cbv;
    #pragma unroll
    for (int j=0;j<4;j++) a += sw[j][dd]*sx[tr+j][dd];
    u[((size_t)(b*Tn)+t0+tr)*512 + d0+dd] = f2b(fsilu(a));
  }
}

// ---------------- scan pass A: thread = (d, half-of-states), h[8] in regs ----------------
__global__ __launch_bounds__(256)
void scanA_k(const u16* __restrict__ delta, const u16* __restrict__ u,
             const float* __restrict__ bcf, const float* __restrict__ aL2,
             float* __restrict__ P, float* __restrict__ CC)
{
  const int ch = blockIdx.x, b = blockIdx.z;
  const int tid = threadIdx.x, lane = tid & 63;
  const int half = lane >> 5;                       // 0: n=0..7, 1: n=8..15
  const int d = blockIdx.y*128 + (tid>>6)*32 + (lane & 31);
  const int t0 = ch*TC;
  float aL[8], h[8];
  #pragma unroll
  for (int i=0;i<2;i++) *(f32x4*)(aL+4*i) = *(const f32x4*)(aL2 + (size_t)d*16 + half*8 + 4*i);
  #pragma unroll
  for (int k=0;k<8;k++) h[k] = 0.f;
  const u16* dp = delta + (size_t)(b*Tn + t0)*512 + d;
  const u16* up = u     + (size_t)(b*Tn + t0)*512 + d;
  const float* bp = bcf + (size_t)(b*Tn + t0)*32 + half*8;
  float sdlt = 0.f;
  #pragma unroll 4
  for (int t=0;t<TC;t++){
    float dlt = b2f(dp[(size_t)t*512]);
    float uu  = b2f(up[(size_t)t*512]);
    float Bv[8];
    *(f32x4*)(Bv)   = *(const f32x4*)(bp + (size_t)t*32);
    *(f32x4*)(Bv+4) = *(const f32x4*)(bp + (size_t)t*32 + 4);
    float du = dlt*uu; sdlt += dlt;
    #pragma unroll
    for (int k=0;k<8;k++)
      h[k] = fmaf(aexp2(dlt*aL[k]), h[k], du*Bv[k]);
  }
  float Pq[8];
  #pragma unroll
  for (int k=0;k<8;k++) Pq[k] = aexp2(sdlt*aL[k]);
  size_t o = (((size_t)((b*CH+ch)*512 + d))<<4) + half*8;
  *(f32x4*)(P +o)   = *(f32x4*)(Pq);
  *(f32x4*)(P +o+4) = *(f32x4*)(Pq+4);
  *(f32x4*)(CC+o)   = *(f32x4*)(h);
  *(f32x4*)(CC+o+4) = *(f32x4*)(h+4);
}

// ---------------- scan pass B: sequential over chunks; P becomes h0 (exclusive) in place ----------------
__global__ __launch_bounds__(256)
void scanB_k(float* __restrict__ P, const float* __restrict__ CC)
{
  const int gid = blockIdx.x*256 + threadIdx.x;   // 32768 threads: (b, d*16+n)
  const int b = gid >> 13, r = gid & 8191;
  const size_t base = (size_t)b*CH*8192 + r;
  float h = 0.f;
  #pragma unroll 4
  for (int ch=0; ch<CH; ch++){
    size_t idx = base + (size_t)ch*8192;
    float Pv = P[idx];
    float cv = CC[idx];
    P[idx] = h;                 // exclusive prefix -> h0
    h = fmaf(Pv, h, cv);
  }
}

// ---------------- scan pass C: thread = (d, half-of-states); recompute with h0, gated y' bf16 ----------------
__global__ __launch_bounds__(256)
void scanC_k(const u16* __restrict__ delta, const u16* __restrict__ u,
             const float* __restrict__ bcf, const u16* __restrict__ z,
             const float* __restrict__ aL2, const float* __restrict__ h0,
             const float* __restrict__ Dp, u16* __restrict__ yg)
{
  const int ch = blockIdx.x, b = blockIdx.z;
  const int tid = threadIdx.x, lane = tid & 63;
  const int half = lane >> 5;                       // 0: n=0..7, 1: n=8..15
  const int d = blockIdx.y*128 + (tid>>6)*32 + (lane & 31);
  const int t0 = ch*TC;
  float aL[8], h[8];
  #pragma unroll
  for (int i=0;i<2;i++) *(f32x4*)(aL+4*i) = *(const f32x4*)(aL2 + (size_t)d*16 + half*8 + 4*i);
  size_t o = (((size_t)((b*CH+ch)*512 + d))<<4) + half*8;
  *(f32x4*)(h)   = *(const f32x4*)(h0+o);
  *(f32x4*)(h+4) = *(const f32x4*)(h0+o+4);
  const float Dd = Dp[d];
  const u16* dp = delta + (size_t)(b*Tn + t0)*512 + d;
  const u16* up = u     + (size_t)(b*Tn + t0)*512 + d;
  const u16* zp = z     + (size_t)(b*Tn + t0)*512 + d;
  const float* bp = bcf + (size_t)(b*Tn + t0)*32 + half*8;
  u16* yp = yg + (size_t)(b*Tn + t0)*512 + d;
  #pragma unroll 2
  for (int t=0;t<TC;t++){
    float dlt = b2f(dp[(size_t)t*512]);
    float uu  = b2f(up[(size_t)t*512]);
    float zz  = b2f(zp[(size_t)t*512]);
    float Bv[8], Cv[8];
    *(f32x4*)(Bv)   = *(const f32x4*)(bp + (size_t)t*32);
    *(f32x4*)(Bv+4) = *(const f32x4*)(bp + (size_t)t*32 + 4);
    *(f32x4*)(Cv)   = *(const f32x4*)(bp + (size_t)t*32 + 16);
    *(f32x4*)(Cv+4) = *(const f32x4*)(bp + (size_t)t*32 + 20);
    float du = dlt*uu;
    float p0=0.f, p1=0.f;
    #pragma unroll
    for (int k=0;k<8;k+=2){
      h[k]   = fmaf(aexp2(dlt*aL[k]),   h[k],   du*Bv[k]);   p0 = fmaf(h[k],   Cv[k],   p0);
      h[k+1] = fmaf(aexp2(dlt*aL[k+1]), h[k+1], du*Bv[k+1]); p1 = fmaf(h[k+1], Cv[k+1], p1);
    }
    float p = p0 + p1;
    p += __shfl_xor(p, 32);
    float gy = (p + uu*Dd) * fsilu(zz);
    if (half == 0) yp[(size_t)t*512] = f2b(gy);
  }
}

extern "C" void kernel_launch(void* const* d_in, const int* in_sizes, int n_in,
                              void* d_out, int out_size, void* d_ws, size_t ws_size,
                              hipStream_t stream)
{
  const float* x    = (const float*)d_in[0];
  const float* lnw  = (const float*)d_in[1];
  const float* lnb  = (const float*)d_in[2];
  const float* inw  = (const float*)d_in[3];
  const float* cw   = (const float*)d_in[4];
  const float* cb   = (const float*)d_in[5];
  const float* xpw  = (const float*)d_in[6];
  const float* dtw  = (const float*)d_in[7];
  const float* dtb  = (const float*)d_in[8];
  const float* alog = (const float*)d_in[9];
  const float* Dp   = (const float*)d_in[10];
  const float* opw  = (const float*)d_in[11];
  float* out = (float*)d_out;
  char* ws = (char*)d_ws;

  u16*   W     = (u16*)(ws + OFF_W);
  float* aL2   = (float*)(ws + OFF_AL2);
  u16*   xn    = (u16*)(ws + OFF_XN);
  u16*   xin   = (u16*)(ws + OFF_XIN);
  u16*   z     = (u16*)(ws + OFF_Z);
  u16*   u     = (u16*)(ws + OFF_U);
  u16*   dblDT = (u16*)(ws + OFF_DBLDT);
  float* bcf   = (float*)(ws + OFF_BCF);
  u16*   delta = (u16*)(ws + OFF_DELTA);
  float* P     = (float*)(ws + OFF_P);
  float* CC    = (float*)(ws + OFF_CC);
  u16*   yg    = xin;   // x_in dead after conv

  wconv_k<<<1760, 256, 0, stream>>>(inw, xpw, dtw, opw, alog, W, aL2);
  ln_k<<<dim3(Tn/64, Bn), 256, 0, stream>>>(x, lnw, lnb, xn);
  // in_proj: (32768x256) @ (1024x256)^T -> split x_in / z
  gemm_k<128,2><<<dim3(MTOT/128, 8), 256, 0, stream>>>(xn, 256, W, 256, xin, z, nullptr, 512, nullptr, 256);
  conv_k<<<dim3(Tn/32, 8, Bn), 256, 0, stream>>>(xin, cw, cb, u);
  // x_proj (padded to N=64): u @ Wxpp^T -> dt bf16 (32/row) + B|C f32 (32/row)
  gemm_k<64,3><<<dim3(MTOT/128, 1), 256, 0, stream>>>(u, 512, W + 262144, 512, dblDT, nullptr, bcf, 0, nullptr, 512);
  // dt_proj (K padded to 32) + softplus -> delta bf16
  gemm_k<128,1><<<dim3(MTOT/128, 4), 256, 0, stream>>>(dblDT, 32, W + 294912, 32, delta, nullptr, nullptr, 512, dtb, 32);
  scanA_k<<<dim3(CH, 4, Bn), 256, 0, stream>>>(delta, u, bcf, aL2, P, CC);
  scanB_k<<<128, 256, 0, stream>>>(P, CC);
  scanC_k<<<dim3(CH, 4, Bn), 256, 0, stream>>>(delta, u, bcf, z, aL2, P, Dp, yg);
  // out_proj fused with transpose+residual: yg @ Wop^T -> out (B,C,T) f32
  gemmot_k<<<dim3(MTOT/128, 2), 256, 0, stream>>>(yg, W + 311296, x, out);
}

// Round 7
// 223.181 us; speedup vs baseline: 1.2644x; 1.2644x over previous
//
#include <hip/hip_runtime.h>

typedef unsigned short u16;
typedef unsigned int u32;
typedef __bf16 bfx8 __attribute__((ext_vector_type(8)));
typedef float f32x4 __attribute__((ext_vector_type(4)));

#define Tn 8192
#define Bn 4
#define MTOT 32768
#define CH 256
#define TC 32

// ---- ws layout (bytes) ----
#define OFF_W     0ul
#define OFF_AL2   917504ul
#define OFF_XN    (1ul<<20)    // 16 MiB
#define OFF_XIN   (17ul<<20)   // 32 MiB (reused as ygated)
#define OFF_Z     (49ul<<20)   // 32 MiB
#define OFF_U     (81ul<<20)   // 32 MiB
#define OFF_DBLDT (113ul<<20)  // 2 MiB  (dt bf16 padded, 32 u16/row)
#define OFF_BCF   (115ul<<20)  // 4 MiB  (B|C f32, 32 f32/row)
#define OFF_DELTA (119ul<<20)  // 32 MiB (delta bf16)
#define OFF_SD    (151ul<<20)  // 2 MiB  (sum-delta per (b,ch,d))
#define OFF_CC    (153ul<<20)  // 32 MiB (chunk carry -> exclusive h0 in place) ; total 185 MiB

__device__ __forceinline__ float b2f(u16 h){ return __uint_as_float(((u32)h)<<16); }
__device__ __forceinline__ u16 f2b(float f){
  u32 u = __float_as_uint(f);
  return (u16)((u + 0x7FFFu + ((u>>16)&1u)) >> 16);
}
__device__ __forceinline__ float aexp2(float x){ float r; asm("v_exp_f32 %0, %1" : "=v"(r) : "v"(x)); return r; }
__device__ __forceinline__ float arcp (float x){ float r; asm("v_rcp_f32 %0, %1" : "=v"(r) : "v"(x)); return r; }
__device__ __forceinline__ float alog2(float x){ float r; asm("v_log_f32 %0, %1" : "=v"(r) : "v"(x)); return r; }
__device__ __forceinline__ float fsilu(float a){ return a*arcp(1.f + aexp2(-a*1.44269504f)); }
__device__ __forceinline__ float fsoftplus(float v){
  float r = 0.69314718f*alog2(1.f + aexp2(v*1.44269504f));
  return (v > 20.f) ? v : r;
}
typedef const __attribute__((address_space(1))) void* gp1_t;
typedef __attribute__((address_space(3))) void* lp3_t;
__device__ __forceinline__ void gload_lds16(const void* g, void* l){
  __builtin_amdgcn_global_load_lds((gp1_t)g, (lp3_t)l, 16, 0, 0);
}

// ---------------- weight convert / pad / A-table ----------------
__global__ void wconv_k(const float* __restrict__ inw, const float* __restrict__ xpw,
                        const float* __restrict__ dtw, const float* __restrict__ opw,
                        const float* __restrict__ alog, u16* __restrict__ W, float* __restrict__ aL2)
{
  int i = blockIdx.x*256 + threadIdx.x;
  if (i < 262144) { W[i] = f2b(inw[i]); return; }                       // in_proj (1024x256)
  if (i < 294912) { int j = i - 262144; int r = j >> 9, k = j & 511;    // x_proj padded (64x512)
    float v = (r < 16) ? xpw[r*512 + k] : ((r < 32) ? 0.f : xpw[(r-16)*512 + k]);
    W[i] = f2b(v); return; }
  if (i < 311296) { int j = i - 294912; int d = j >> 5, k = j & 31;     // dt_proj padded (512x32)
    W[i] = f2b((k < 16) ? dtw[d*16 + k] : 0.f); return; }
  if (i < 442368) { W[i] = f2b(opw[i - 311296]); return; }              // out_proj (256x512)
  if (i < 450560) { int j = i - 442368; aL2[j] = -__expf(alog[j]) * 1.44269504088896f; return; }
}

// ---------------- LayerNorm over C, write xn (B,T,C) bf16 ----------------
__global__ __launch_bounds__(256)
void ln_k(const float* __restrict__ x, const float* __restrict__ lnw,
          const float* __restrict__ lnb, u16* __restrict__ xn)
{
  const int t0 = blockIdx.x*64, b = blockIdx.y;
  const int tid = threadIdx.x, cg = tid>>6, tl = tid&63;
  __shared__ float ps[4][64], pq[4][64], mu[64], rs[64];
  float s = 0.f, q = 0.f;
  for (int ci = 0; ci < 64; ci++){
    int c = ci*4 + cg;
    float v = x[((size_t)(b*256 + c))*Tn + t0 + tl];
    s += v; q += v*v;
  }
  ps[cg][tl] = s; pq[cg][tl] = q;
  __syncthreads();
  if (tid < 64){
    float S = ps[0][tid]+ps[1][tid]+ps[2][tid]+ps[3][tid];
    float Q = pq[0][tid]+pq[1][tid]+pq[2][tid]+pq[3][tid];
    float m = S*(1.f/256.f);
    float var = Q*(1.f/256.f) - m*m;
    mu[tid] = m; rs[tid] = rsqrtf(var + 1e-5f);
  }
  __syncthreads();
  const float w = lnw[tid&255], bb = lnb[tid&255];
  for (int t = 0; t < 64; t++){
    float v = x[((size_t)(b*256 + tid))*Tn + t0 + t];
    xn[((size_t)(b*Tn) + t0 + t)*256 + tid] = f2b((v - mu[t])*rs[t]*w + bb);
  }
}

// ---------------- generic bf16 MFMA GEMM: out[m][n] = sum_k A[m][k]*Bw[n][k] ----------------
// EPI 1: softplus(v+bias[n]) bf16 ; 2: split col<512->O else O2 ; 3: col<32->O bf16 (32/row) else Of f32 (32/row)
template<int BN, int EPI>
__global__ __launch_bounds__(256)
void gemm_k(const u16* __restrict__ A, int lda,
            const u16* __restrict__ Bw, int ldb,
            u16* __restrict__ O, u16* __restrict__ O2, float* __restrict__ Of, int ldo,
            const float* __restrict__ bias, int K)
{
  constexpr int NFR = BN/32;
  __shared__ __align__(16) u16 sA[128*32];
  __shared__ __align__(16) u16 sB[BN*32];
  const int tid = threadIdx.x;
  const int m0 = blockIdx.x*128, n0 = blockIdx.y*BN;
  const int lane = tid & 63, wid = tid >> 6;
  const int wr = wid >> 1, wc = wid & 1;
  const int lr = lane & 15, g = lane >> 4;
  const f32x4 fz = {0.f,0.f,0.f,0.f};
  f32x4 acc[4][NFR];
  #pragma unroll
  for (int m=0;m<4;m++)
    #pragma unroll
    for (int n=0;n<NFR;n++) acc[m][n] = fz;
  const int nk = K >> 5;
  for (int kt = 0; kt < nk; ++kt){
    __syncthreads();
    #pragma unroll
    for (int i=0;i<2;i++){ int ci = i*256 + tid;
      gload_lds16(A + (size_t)(m0+(ci>>2))*lda + kt*32 + (ci&3)*8, sA + ci*8); }
    #pragma unroll
    for (int i=0;i<BN/64;i++){ int ci = i*256 + tid;
      gload_lds16(Bw + (size_t)(n0+(ci>>2))*ldb + kt*32 + (ci&3)*8, sB + ci*8); }
    __syncthreads();
    bfx8 af[4], bf[NFR];
    #pragma unroll
    for (int m=0;m<4;m++) af[m] = *(const bfx8*)(sA + (wr*64 + m*16 + lr)*32 + g*8);
    #pragma unroll
    for (int n=0;n<NFR;n++) bf[n] = *(const bfx8*)(sB + (wc*(BN/2) + n*16 + lr)*32 + g*8);
    #pragma unroll
    for (int m=0;m<4;m++)
      #pragma unroll
      for (int n=0;n<NFR;n++)
        acc[m][n] = __builtin_amdgcn_mfma_f32_16x16x32_bf16(af[m], bf[n], acc[m][n], 0, 0, 0);
  }
  #pragma unroll
  for (int m=0;m<4;m++)
    #pragma unroll
    for (int n=0;n<NFR;n++)
      #pragma unroll
      for (int r=0;r<4;r++){
        int row = m0 + wr*64 + m*16 + g*4 + r;
        int col = n0 + wc*(BN/2) + n*16 + lr;
        float v = acc[m][n][r];
        if (EPI == 1){
          O[(size_t)row*ldo + col] = f2b(fsoftplus(v + bias[col]));
        } else if (EPI == 2){
          if (col < 512) O[(size_t)row*512 + col] = f2b(v);
          else           O2[(size_t)row*512 + (col-512)] = f2b(v);
        } else {
          if (col < 32) O[(size_t)row*32 + col] = f2b(v);
          else          Of[(size_t)row*32 + (col-32)] = v;
        }
      }
}

// ---------------- out_proj GEMM fused with transpose + residual: out (B,C,T) f32 ----------------
__global__ __launch_bounds__(256)
void gemmot_k(const u16* __restrict__ A, const u16* __restrict__ Bw,
              const float* __restrict__ x, float* __restrict__ out)
{
  __shared__ __align__(16) u16 sA[128*32];
  __shared__ __align__(16) u16 sB[128*32];
  __shared__ float st[64][129];
  const int tid = threadIdx.x;
  const int m0 = blockIdx.x*128, n0 = blockIdx.y*128;
  const int lane = tid & 63, wid = tid >> 6;
  const int wr = wid >> 1, wc = wid & 1;
  const int lr = lane & 15, g = lane >> 4;
  const f32x4 fz = {0.f,0.f,0.f,0.f};
  f32x4 acc[4][4];
  #pragma unroll
  for (int m=0;m<4;m++)
    #pragma unroll
    for (int n=0;n<4;n++) acc[m][n] = fz;
  for (int kt = 0; kt < 16; ++kt){
    __syncthreads();
    #pragma unroll
    for (int i=0;i<2;i++){ int ci = i*256 + tid;
      gload_lds16(A + (size_t)(m0+(ci>>2))*512 + kt*32 + (ci&3)*8, sA + ci*8); }
    #pragma unroll
    for (int i=0;i<2;i++){ int ci = i*256 + tid;
      gload_lds16(Bw + (size_t)(n0+(ci>>2))*512 + kt*32 + (ci&3)*8, sB + ci*8); }
    __syncthreads();
    bfx8 af[4], bf[4];
    #pragma unroll
    for (int m=0;m<4;m++) af[m] = *(const bfx8*)(sA + (wr*64 + m*16 + lr)*32 + g*8);
    #pragma unroll
    for (int n=0;n<4;n++) bf[n] = *(const bfx8*)(sB + (wc*64 + n*16 + lr)*32 + g*8);
    #pragma unroll
    for (int m=0;m<4;m++)
      #pragma unroll
      for (int n=0;n<4;n++)
        acc[m][n] = __builtin_amdgcn_mfma_f32_16x16x32_bf16(af[m], bf[n], acc[m][n], 0, 0, 0);
  }
  const int b = m0 >> 13, t0 = m0 & 8191;
  const int tl = tid & 63, cgrp = tid >> 6;
  for (int hf=0; hf<2; hf++){
    __syncthreads();
    if (wr == hf){
      #pragma unroll
      for (int m=0;m<4;m++)
        #pragma unroll
        for (int n=0;n<4;n++)
          #pragma unroll
          for (int r=0;r<4;r++)
            st[m*16 + g*4 + r][wc*64 + n*16 + lr] = acc[m][n][r];
    }
    __syncthreads();
    const int tg = t0 + hf*64 + tl;
    #pragma unroll
    for (int ci=0; ci<32; ci++){
      int c = cgrp*32 + ci;
      size_t oa = ((size_t)(b*256) + n0 + c)*Tn + tg;
      out[oa] = st[tl][c] + x[oa];
    }
  }
}

// ---------------- causal depthwise conv (k=4) + bias + silu -> u bf16 ----------------
__global__ __launch_bounds__(256)
void conv_k(const u16* __restrict__ xin, const float* __restrict__ cw,
            const float* __restrict__ cb, u16* __restrict__ u)
{
  const int t0 = blockIdx.x*32, d0 = blockIdx.y*64, b = blockIdx.z;
  const int tid = threadIdx.x;
  __shared__ float sx[35][64];
  __shared__ float sw[4][64];
  { int d = tid>>2, j = tid&3; sw[j][d] = cw[(d0+d)*4 + j]; }
  for (int i=0;i<9;i++){ int f = i*256 + tid; if (f < 35*64){
      int r = f>>6, dd = f&63; int t = t0 - 3 + r;
      sx[r][dd] = (t >= 0) ? b2f(xin[((size_t)(b*Tn)+t)*512 + d0+dd]) : 0.f; } }
  __syncthreads();
  const float cbv = cb[d0 + (tid&63)];
  for (int oi=0; oi<8; oi++){
    int f = oi*256 + tid; int tr = f>>6, dd = f&63;
    float a = cbv;
    #pragma unroll
    for (int j=0;j<4;j++) a += sw[j][dd]*sx[tr+j][dd];
    u[((size_t)(b*Tn)+t0+tr)*512 + d0+dd] = f2b(fsilu(a));
  }
}

// log-depth powers r^1..r^16 -> e[16]
__device__ __forceinline__ void powtree(float r1, float* e){
  float r2 = r1*r1;
  float r3 = r2*r1, r4 = r2*r2;
  float r5 = r4*r1, r6 = r4*r2, r7 = r4*r3, r8 = r4*r4;
  e[0]=r1; e[1]=r2; e[2]=r3; e[3]=r4; e[4]=r5; e[5]=r6; e[6]=r7; e[7]=r8;
  #pragma unroll
  for (int k=0;k<8;k++) e[8+k] = r8*e[k];
}

// ---------------- scan pass A: thread-per-d, h[16] in regs; writes sum-delta + chunk carry ----------------
__global__ __launch_bounds__(256)
void scanA_k(const u16* __restrict__ delta, const u16* __restrict__ u,
             const float* __restrict__ bcf, const float* __restrict__ aL2,
             float* __restrict__ SD, float* __restrict__ CC)
{
  const int ch = blockIdx.x, d = blockIdx.y*256 + threadIdx.x, b = blockIdx.z;
  const int t0 = ch*TC;
  float aL[16], h[16];
  #pragma unroll
  for (int i=0;i<4;i++) *(f32x4*)(aL+4*i) = *(const f32x4*)(aL2 + (size_t)d*16 + 4*i);
  #pragma unroll
  for (int n=0;n<16;n++) h[n] = 0.f;
  bool st = true;
  #pragma unroll
  for (int n=1;n<16;n++) st = st && (fabsf(aL[n] - (n+1)*aL[0]) <= 2e-4f*fabsf(aL[n]));
  const u16* dp = delta + (size_t)(b*Tn + t0)*512 + d;
  const u16* up = u     + (size_t)(b*Tn + t0)*512 + d;
  const float* bp = bcf + (size_t)(b*Tn + t0)*32;
  float sdlt = 0.f;
  const float aL0 = aL[0];
  if (st){
    #pragma unroll 4
    for (int t=0;t<TC;t++){
      float dlt = b2f(dp[(size_t)t*512]);
      float uu  = b2f(up[(size_t)t*512]);
      float Bv[16];
      #pragma unroll
      for (int i=0;i<4;i++) *(f32x4*)(Bv+4*i) = *(const f32x4*)(bp + (size_t)t*32 + 4*i);
      float du = dlt*uu; sdlt += dlt;
      float e[16];
      powtree(aexp2(dlt*aL0), e);
      #pragma unroll
      for (int n=0;n<16;n++)
        h[n] = fmaf(e[n], h[n], du*Bv[n]);
    }
  } else {
    #pragma unroll 2
    for (int t=0;t<TC;t++){
      float dlt = b2f(dp[(size_t)t*512]);
      float uu  = b2f(up[(size_t)t*512]);
      float Bv[16];
      #pragma unroll
      for (int i=0;i<4;i++) *(f32x4*)(Bv+4*i) = *(const f32x4*)(bp + (size_t)t*32 + 4*i);
      float du = dlt*uu; sdlt += dlt;
      #pragma unroll
      for (int n=0;n<16;n++)
        h[n] = fmaf(aexp2(dlt*aL[n]), h[n], du*Bv[n]);
    }
  }
  SD[(size_t)(b*CH+ch)*512 + d] = sdlt;
  size_t o = ((size_t)((b*CH+ch)*512 + d))<<4;
  #pragma unroll
  for (int i=0;i<4;i++)
    *(f32x4*)(CC+o+4*i) = *(f32x4*)(h +4*i);
}

// ---------------- scan pass B: sequential over chunks; CC becomes exclusive h0 in place ----------------
__global__ __launch_bounds__(256)
void scanB_k(const float* __restrict__ SD, const float* __restrict__ aL2, float* __restrict__ CC)
{
  const int gid = blockIdx.x*256 + threadIdx.x;   // 32768 threads: (b, d*16+n)
  const int b = gid >> 13, r = gid & 8191;        // r = d*16+n
  const float aL = aL2[r];
  const float* sdp = SD + (size_t)b*CH*512 + (r>>4);
  const size_t base = (size_t)b*CH*8192 + r;
  float h = 0.f;
  for (int ch=0; ch<CH; ch++){
    float Pv = aexp2(sdp[(size_t)ch*512] * aL);
    size_t idx = base + (size_t)ch*8192;
    float cv = CC[idx];
    CC[idx] = h;                 // exclusive prefix -> h0
    h = fmaf(Pv, h, cv);
  }
}

// ---------------- scan pass C: recompute with h0, produce gated y' bf16 ----------------
__global__ __launch_bounds__(256)
void scanC_k(const u16* __restrict__ delta, const u16* __restrict__ u,
             const float* __restrict__ bcf, const u16* __restrict__ z,
             const float* __restrict__ aL2, const float* __restrict__ h0,
             const float* __restrict__ Dp, u16* __restrict__ yg)
{
  const int ch = blockIdx.x, d = blockIdx.y*256 + threadIdx.x, b = blockIdx.z;
  const int t0 = ch*TC;
  float aL[16], h[16];
  #pragma unroll
  for (int i=0;i<4;i++) *(f32x4*)(aL+4*i) = *(const f32x4*)(aL2 + (size_t)d*16 + 4*i);
  size_t o = ((size_t)((b*CH+ch)*512 + d))<<4;
  #pragma unroll
  for (int i=0;i<4;i++) *(f32x4*)(h+4*i) = *(const f32x4*)(h0+o+4*i);
  bool st = true;
  #pragma unroll
  for (int n=1;n<16;n++) st = st && (fabsf(aL[n] - (n+1)*aL[0]) <= 2e-4f*fabsf(aL[n]));
  const float Dd = Dp[d];
  const float aL0 = aL[0];
  const u16* dp = delta + (size_t)(b*Tn + t0)*512 + d;
  const u16* up = u     + (size_t)(b*Tn + t0)*512 + d;
  const u16* zp = z     + (size_t)(b*Tn + t0)*512 + d;
  const float* bp = bcf + (size_t)(b*Tn + t0)*32;
  u16* yp = yg + (size_t)(b*Tn + t0)*512 + d;
  if (st){
    #pragma unroll 2
    for (int t=0;t<TC;t++){
      float dlt = b2f(dp[(size_t)t*512]);
      float uu  = b2f(up[(size_t)t*512]);
      float zz  = b2f(zp[(size_t)t*512]);
      float Bv[16], Cv[16];
      #pragma unroll
      for (int i=0;i<4;i++){
        *(f32x4*)(Bv+4*i) = *(const f32x4*)(bp + (size_t)t*32 + 4*i);
        *(f32x4*)(Cv+4*i) = *(const f32x4*)(bp + (size_t)t*32 + 16 + 4*i);
      }
      float du = dlt*uu;
      float e[16];
      powtree(aexp2(dlt*aL0), e);
      float p0=0.f, p1=0.f, p2=0.f, p3=0.f;
      #pragma unroll
      for (int n=0;n<16;n+=4){
        h[n]   = fmaf(e[n],   h[n],   du*Bv[n]);   p0 = fmaf(h[n],   Cv[n],   p0);
        h[n+1] = fmaf(e[n+1], h[n+1], du*Bv[n+1]); p1 = fmaf(h[n+1], Cv[n+1], p1);
        h[n+2] = fmaf(e[n+2], h[n+2], du*Bv[n+2]); p2 = fmaf(h[n+2], Cv[n+2], p2);
        h[n+3] = fmaf(e[n+3], h[n+3], du*Bv[n+3]); p3 = fmaf(h[n+3], Cv[n+3], p3);
      }
      float p = (p0+p1) + (p2+p3);
      float gy = (p + uu*Dd) * fsilu(zz);
      yp[(size_t)t*512] = f2b(gy);
    }
  } else {
    #pragma unroll 2
    for (int t=0;t<TC;t++){
      float dlt = b2f(dp[(size_t)t*512]);
      float uu  = b2f(up[(size_t)t*512]);
      float zz  = b2f(zp[(size_t)t*512]);
      float Bv[16], Cv[16];
      #pragma unroll
      for (int i=0;i<4;i++){
        *(f32x4*)(Bv+4*i) = *(const f32x4*)(bp + (size_t)t*32 + 4*i);
        *(f32x4*)(Cv+4*i) = *(const f32x4*)(bp + (size_t)t*32 + 16 + 4*i);
      }
      float du = dlt*uu;
      float p0 = 0.f;
      #pragma unroll
      for (int n=0;n<16;n++){
        h[n] = fmaf(aexp2(dlt*aL[n]), h[n], du*Bv[n]);
        p0 = fmaf(h[n], Cv[n], p0);
      }
      float gy = (p0 + uu*Dd) * fsilu(zz);
      yp[(size_t)t*512] = f2b(gy);
    }
  }
}

extern "C" void kernel_launch(void* const* d_in, const int* in_sizes, int n_in,
                              void* d_out, int out_size, void* d_ws, size_t ws_size,
                              hipStream_t stream)
{
  const float* x    = (const float*)d_in[0];
  const float* lnw  = (const float*)d_in[1];
  const float* lnb  = (const float*)d_in[2];
  const float* inw  = (const float*)d_in[3];
  const float* cw   = (const float*)d_in[4];
  const float* cb   = (const float*)d_in[5];
  const float* xpw  = (const float*)d_in[6];
  const float* dtw  = (const float*)d_in[7];
  const float* dtb  = (const float*)d_in[8];
  const float* alog = (const float*)d_in[9];
  const float* Dp   = (const float*)d_in[10];
  const float* opw  = (const float*)d_in[11];
  float* out = (float*)d_out;
  char* ws = (char*)d_ws;

  u16*   W     = (u16*)(ws + OFF_W);
  float* aL2   = (float*)(ws + OFF_AL2);
  u16*   xn    = (u16*)(ws + OFF_XN);
  u16*   xin   = (u16*)(ws + OFF_XIN);
  u16*   z     = (u16*)(ws + OFF_Z);
  u16*   u     = (u16*)(ws + OFF_U);
  u16*   dblDT = (u16*)(ws + OFF_DBLDT);
  float* bcf   = (float*)(ws + OFF_BCF);
  u16*   delta = (u16*)(ws + OFF_DELTA);
  float* SD    = (float*)(ws + OFF_SD);
  float* CC    = (float*)(ws + OFF_CC);
  u16*   yg    = xin;   // x_in dead after conv

  wconv_k<<<1760, 256, 0, stream>>>(inw, xpw, dtw, opw, alog, W, aL2);
  ln_k<<<dim3(Tn/64, Bn), 256, 0, stream>>>(x, lnw, lnb, xn);
  // in_proj: (32768x256) @ (1024x256)^T -> split x_in / z
  gemm_k<128,2><<<dim3(MTOT/128, 8), 256, 0, stream>>>(xn, 256, W, 256, xin, z, nullptr, 512, nullptr, 256);
  conv_k<<<dim3(Tn/32, 8, Bn), 256, 0, stream>>>(xin, cw, cb, u);
  // x_proj (padded to N=64): u @ Wxpp^T -> dt bf16 (32/row) + B|C f32 (32/row)
  gemm_k<64,3><<<dim3(MTOT/128, 1), 256, 0, stream>>>(u, 512, W + 262144, 512, dblDT, nullptr, bcf, 0, nullptr, 512);
  // dt_proj (K padded to 32) + softplus -> delta bf16
  gemm_k<128,1><<<dim3(MTOT/128, 4), 256, 0, stream>>>(dblDT, 32, W + 294912, 32, delta, nullptr, nullptr, 512, dtb, 32);
  scanA_k<<<dim3(CH, 2, Bn), 256, 0, stream>>>(delta, u, bcf, aL2, SD, CC);
  scanB_k<<<128, 256, 0, stream>>>(SD, aL2, CC);
  scanC_k<<<dim3(CH, 2, Bn), 256, 0, stream>>>(delta, u, bcf, z, aL2, CC, Dp, yg);
  // out_proj fused with transpose+residual: yg @ Wop^T -> out (B,C,T) f32
  gemmot_k<<<dim3(MTOT/128, 2), 256, 0, stream>>>(yg, W + 311296, x, out);
}